// Round 2
// 854.402 us; speedup vs baseline: 1.1248x; 1.1248x over previous
//
#include <hip/hip_runtime.h>
#include <cstdint>

// Problem constants (fixed dataset: setup_inputs in reference)
constexpr int B = 8, N = 100000, G = 64, T = 256, TOPK = 27;
constexpr int BN = B * N;
constexpr int CAP = 2048;           // candidate LDS capacity per gt
#define NEG_INF_VAL (-100000000.0f) // -INF in reference, exactly representable

typedef float v4f __attribute__((ext_vector_type(4)));

// ---------------------------------------------------------------------------
// Kernel 0: precompute anchor centers (float2) once, and zero the best[]
// buffer (folds the former hipMemsetAsync dispatch into this one).
// Same center formula as the assign/iou phases so distances are bit-identical.
// ---------------------------------------------------------------------------
__global__ __launch_bounds__(256) void atss_centers_kernel(
    const float* __restrict__ anchors, float2* __restrict__ ctr,
    unsigned long long* __restrict__ best)
{
#pragma clang fp contract(off)
  int i = blockIdx.x * 256 + threadIdx.x;
  if (i < BN) {
    float4 ab = ((const float4*)anchors)[i];
    ctr[i] = make_float2((ab.z + ab.x) * 0.5f, (ab.w + ab.y) * 0.5f);
    best[i] = 0ULL;
  }
}

// ---------------------------------------------------------------------------
// Kernel A: one block per (b,g). Exact top-27 nearest anchors by center
// distance (tie-break: lower index, matching lax.top_k), candidate IoUs,
// mean + unbiased std threshold, center-inside test, packed atomicMax
// scatter into per-anchor best buffer.
// packed = (f32bits(iou) << 32) | (0xFFFFFFFF - g)
//   -> max = largest iou; tie -> smallest g (matches jnp.argmax first-max).
// packed == 0 means "unmatched" (positives always have iou > 0).
//
// 1024 threads/block (32 waves/CU instead of 8 -> 4x MLP for the
// latency-bound scan), d^2 prefilter (sqrt only at insertion; stored d is the
// bit-identical __fsqrt_rn of the identical d^2 expression), float4 center
// loads (2 anchors/iter), and a bijective XCD swizzle so batch b's 800 KB
// center slice stays resident in XCD b's L2.
// ---------------------------------------------------------------------------
__global__ __launch_bounds__(1024) void atss_assign_kernel(
    const float* __restrict__ anchors,     // [B,N,4]
    const float2* __restrict__ ctr,        // [B,N]
    const float* __restrict__ gts,         // [B,G,4]
    unsigned long long* __restrict__ best) // [B*N]
{
#pragma clang fp contract(off)
  __shared__ float s_d[CAP];
  __shared__ int   s_i[CAP];
  __shared__ int   s_cnt;
  __shared__ int   s_sel[TOPK];
  __shared__ float s_iou[TOPK];
  __shared__ int   s_in[TOPK];
  __shared__ float s_thresh;

  // XCD-bijective swizzle: blocks with bid%8==k land on XCD k; map them to
  // batch k (G=64 blocks per batch, 512 = 8*64 total, bijective).
  const int bid = blockIdx.x;
  const int bg  = (bid & 7) * (B * G / 8) + (bid >> 3);
  const int b   = bg / G;
  const int g   = bg % G;
  const int tid = threadIdx.x;

  const float4 gbox = ((const float4*)gts)[bg];
  const float g_cx = (gbox.z + gbox.x) * 0.5f;
  const float g_cy = (gbox.w + gbox.y) * 0.5f;

  const float4*  abase = (const float4*)(anchors + (size_t)b * N * 4);
  const float2*  cbase = ctr + (size_t)b * N;
  const float4*  c4    = (const float4*)cbase;   // 2 anchor centers per load

  // --- Candidate collection: all anchors with d^2 < thr^2 (exact count). ---
  // If the radius captures >= 27 anchors, the true top-27 are all in the set.
  float thr2 = 24.0f * 24.0f;
  int M = 0;
  for (int attempt = 0; attempt < 8; ++attempt) {
    if (tid == 0) s_cnt = 0;
    __syncthreads();
    for (int m = tid; m < N / 2; m += 1024) {
      float4 c = c4[m];
      float dx0 = c.x - g_cx, dy0 = c.y - g_cy;
      float d20 = __fmul_rn(dx0, dx0) + __fmul_rn(dy0, dy0);
      float dx1 = c.z - g_cx, dy1 = c.w - g_cy;
      float d21 = __fmul_rn(dx1, dx1) + __fmul_rn(dy1, dy1);
      if (d20 < thr2) {
        int p = atomicAdd(&s_cnt, 1);
        if (p < CAP) { s_d[p] = __fsqrt_rn(d20); s_i[p] = 2 * m; }
      }
      if (d21 < thr2) {
        int p = atomicAdd(&s_cnt, 1);
        if (p < CAP) { s_d[p] = __fsqrt_rn(d21); s_i[p] = 2 * m + 1; }
      }
    }
    __syncthreads();
    int cnt = s_cnt;
    __syncthreads();
    if (cnt >= TOPK && cnt <= CAP) { M = cnt; break; }
    thr2 = (cnt < TOPK) ? thr2 * 16.0f : thr2 * 0.25f;
  }

  // --- Exact top-27 by rank counting over (d, idx) lexicographic keys. ---
  // Keys are distinct (idx unique) -> ranks unique; rank k = k-th nearest,
  // same order lax.top_k produces (preserves mean/std sum order).
  for (int s = tid; s < M; s += 1024) {
    unsigned long long pk_s =
        ((unsigned long long)__float_as_uint(s_d[s]) << 20) |
        (unsigned long long)(unsigned)s_i[s];
    int rank = 0;
    for (int j = 0; j < M; ++j) {
      unsigned long long pk_j =
          ((unsigned long long)__float_as_uint(s_d[j]) << 20) |
          (unsigned long long)(unsigned)s_i[j];
      rank += (pk_j < pk_s) ? 1 : 0;
    }
    if (rank < TOPK) s_sel[rank] = s_i[s];
  }
  __syncthreads();

  // --- Candidate IoU + center-inside test. ---
  if (tid < TOPK) {
    int a = s_sel[tid];
    float4 ab = abase[a];
    float area_a = __fmul_rn(ab.z - ab.x, ab.w - ab.y);
    float area_b = __fmul_rn(gbox.z - gbox.x, gbox.w - gbox.y);
    float ltx = fmaxf(ab.x, gbox.x), lty = fmaxf(ab.y, gbox.y);
    float rbx = fminf(ab.z, gbox.z), rby = fminf(ab.w, gbox.w);
    float w = fmaxf(rbx - ltx, 0.0f), h = fmaxf(rby - lty, 0.0f);
    float inter = __fmul_rn(w, h);
    float uni = (area_a + area_b) - inter;
    s_iou[tid] = inter / uni;
    float acx = (ab.z + ab.x) * 0.5f, acy = (ab.w + ab.y) * 0.5f;
    float l = acx - gbox.x, t = acy - gbox.y;
    float r = gbox.z - acx, bt = gbox.w - acy;
    float mn = fminf(fminf(l, t), fminf(r, bt));
    s_in[tid] = (mn > 0.01f) ? 1 : 0;
  }
  __syncthreads();

  // --- mean + unbiased std threshold (ddof=1). Same order as reference. ---
  if (tid == 0) {
    float sum = 0.0f;
    for (int k = 0; k < TOPK; ++k) sum += s_iou[k];
    float mean = sum / (float)TOPK;
    float vs = 0.0f;
    for (int k = 0; k < TOPK; ++k) {
      float d = s_iou[k] - mean;
      vs += __fmul_rn(d, d);
    }
    float sd = __fsqrt_rn(vs / (float)(TOPK - 1));
    s_thresh = mean + sd;
  }
  __syncthreads();

  // --- Scatter positives. ---
  if (tid < TOPK) {
    float iou = s_iou[tid];
    if (s_in[tid] && iou >= s_thresh) {
      unsigned long long pk =
          ((unsigned long long)__float_as_uint(iou) << 32) |
          (unsigned long long)(0xFFFFFFFFu - (unsigned)g);
      atomicMax(&best[(size_t)b * N + s_sel[tid]], pk);
    }
  }
}

// ---------------------------------------------------------------------------
// Kernel B: one block per 256 anchors.
// Phase 1: coalesced best[] load; emit val/idx (dword) and matched_gts
//          (float4) coalesced; stash matched token row index in LDS.
// Phase 2: 64 steps x 4 anchors: block cooperatively streams token rows,
//          4 KB contiguous store per step; loads independent -> pipelined.
// All output stores are non-temporal: 838 MB streamed, never re-read, so
// skip L2 allocation churn.
// ---------------------------------------------------------------------------
__global__ __launch_bounds__(256) void atss_write_kernel(
    const unsigned long long* __restrict__ best, // [B*N]
    const float* __restrict__ gts,               // [B,G,4]
    const float* __restrict__ tokens,            // [B,G,T]
    float* __restrict__ out)
{
  float* __restrict__ out_val = out;
  float* __restrict__ out_idx = out + (size_t)BN;
  float* __restrict__ out_mg  = out + (size_t)2 * BN;
  float* __restrict__ out_tok = out + (size_t)6 * BN;

  __shared__ int s_row[256]; // gt row (b*G+g) if matched, else -1

  const int tid = threadIdx.x;
  const int i0  = blockIdx.x * 256;
  const int i   = i0 + tid;

  // --- Phase 1 ---
  unsigned long long p = best[i];
  const int b_ = i / N;
  int g = 0;
  float val = NEG_INF_VAL;
  if (p != 0ULL) {
    g   = (int)(0xFFFFFFFFu - (unsigned)(p & 0xFFFFFFFFULL));
    val = __uint_as_float((unsigned)(p >> 32));
  }
  const int row = b_ * G + g; // unmatched -> g=0 (matches argmax of all -INF)
  s_row[tid] = (p != 0ULL) ? row : -1;

  __builtin_nontemporal_store(val, out_val + i);
  __builtin_nontemporal_store((float)g, out_idx + i);
  v4f mg = ((const v4f*)gts)[row];
  __builtin_nontemporal_store(mg, (v4f*)out_mg + i);
  __syncthreads();

  // --- Phase 2: token rows ---
  const int lane = tid & 63;
  const int sub  = tid >> 6; // 0..3: which anchor within the step
  const v4f* tok4 = (const v4f*)tokens;
#pragma unroll 4
  for (int s = 0; s < 64; ++s) {
    int a = (s << 2) + sub;
    int r = s_row[a];
    v4f t;
    if (r >= 0) {
      t = tok4[(size_t)r * 64 + lane];
    } else {
      t = (v4f){0.0f, 0.0f, 0.0f, 0.0f};
      if (lane == 63) t.w = 1.0f; // unmatched one-hot at token T-1
    }
    __builtin_nontemporal_store(t, (v4f*)(out_tok + (size_t)(i0 + a) * T) + lane);
  }
}

extern "C" void kernel_launch(void* const* d_in, const int* in_sizes, int n_in,
                              void* d_out, int out_size, void* d_ws, size_t ws_size,
                              hipStream_t stream) {
  const float* anchors = (const float*)d_in[0]; // [B,N,4]
  const float* gts     = (const float*)d_in[1]; // [B,G,4]
  const float* tokens  = (const float*)d_in[2]; // [B,G,T]
  float* out = (float*)d_out;

  unsigned long long* best = (unsigned long long*)d_ws;        // B*N u64 = 6.4 MB
  float2* ctr = (float2*)((char*)d_ws + sizeof(unsigned long long) * (size_t)BN);

  atss_centers_kernel<<<BN / 256, 256, 0, stream>>>(anchors, ctr, best);
  atss_assign_kernel<<<B * G, 1024, 0, stream>>>(anchors, ctr, gts, best);
  atss_write_kernel<<<BN / 256, 256, 0, stream>>>(best, gts, tokens, out);
}

// Round 3
// 846.734 us; speedup vs baseline: 1.1350x; 1.0091x over previous
//
#include <hip/hip_runtime.h>
#include <cstdint>

// Problem constants (fixed dataset: setup_inputs in reference)
constexpr int B = 8, N = 100000, G = 64, T = 256, TOPK = 27;
constexpr int BN = B * N;
constexpr int CAP = 2048;           // candidate LDS capacity per gt
#define NEG_INF_VAL (-100000000.0f) // -INF in reference, exactly representable

typedef float v4f __attribute__((ext_vector_type(4)));

// ---------------------------------------------------------------------------
// Kernel 0: precompute anchor centers (float2) once, and zero the best[]
// buffer (folds the former hipMemsetAsync dispatch into this one).
// Same center formula as the assign/iou phases so distances are bit-identical.
// ---------------------------------------------------------------------------
__global__ __launch_bounds__(256) void atss_centers_kernel(
    const float* __restrict__ anchors, float2* __restrict__ ctr,
    unsigned long long* __restrict__ best)
{
#pragma clang fp contract(off)
  int i = blockIdx.x * 256 + threadIdx.x;
  if (i < BN) {
    float4 ab = ((const float4*)anchors)[i];
    ctr[i] = make_float2((ab.z + ab.x) * 0.5f, (ab.w + ab.y) * 0.5f);
    best[i] = 0ULL;
  }
}

// ---------------------------------------------------------------------------
// Kernel A: one block per (b,g). Exact top-27 nearest anchors by center
// distance (tie-break: lower index, matching lax.top_k), candidate IoUs,
// mean + unbiased std threshold, center-inside test, packed atomicMax
// scatter into per-anchor best buffer.
// packed = (f32bits(iou) << 32) | (0xFFFFFFFF - g)
//   -> max = largest iou; tie -> smallest g (matches jnp.argmax first-max).
// packed == 0 means "unmatched" (positives always have iou > 0).
//
// Scan: 2x manually-unrolled float4 center loads (4 anchors/iter, 2
// independent loads in flight per wave) for the latency-bound sweep.
// Insertion order into s_d/s_i is irrelevant: selection rank-counts over
// (d, idx) lexicographic keys, which is order-independent.
// ---------------------------------------------------------------------------
__global__ __launch_bounds__(1024) void atss_assign_kernel(
    const float* __restrict__ anchors,     // [B,N,4]
    const float2* __restrict__ ctr,        // [B,N]
    const float* __restrict__ gts,         // [B,G,4]
    unsigned long long* __restrict__ best) // [B*N]
{
#pragma clang fp contract(off)
  __shared__ float s_d[CAP];
  __shared__ int   s_i[CAP];
  __shared__ int   s_cnt;
  __shared__ int   s_sel[TOPK];
  __shared__ float s_iou[TOPK];
  __shared__ int   s_in[TOPK];
  __shared__ float s_thresh;

  // XCD-bijective swizzle: blocks with bid%8==k land on XCD k; map them to
  // batch k (G=64 blocks per batch, 512 = 8*64 total, bijective).
  const int bid = blockIdx.x;
  const int bg  = (bid & 7) * (B * G / 8) + (bid >> 3);
  const int b   = bg / G;
  const int g   = bg % G;
  const int tid = threadIdx.x;

  const float4 gbox = ((const float4*)gts)[bg];
  const float g_cx = (gbox.z + gbox.x) * 0.5f;
  const float g_cy = (gbox.w + gbox.y) * 0.5f;

  const float4*  abase = (const float4*)(anchors + (size_t)b * N * 4);
  const float2*  cbase = ctr + (size_t)b * N;
  const float4*  c4    = (const float4*)cbase;   // 2 anchor centers per load

  // --- Candidate collection: all anchors with d^2 < thr^2 (exact count). ---
  // If the radius captures >= 27 anchors, the true top-27 are all in the set.
  float thr2 = 24.0f * 24.0f;
  int M = 0;
  for (int attempt = 0; attempt < 8; ++attempt) {
    if (tid == 0) s_cnt = 0;
    __syncthreads();
    // 4 anchors per iteration: two independent float4 loads in flight.
    for (int m = tid; m < N / 4; m += 1024) {
      float4 ca = c4[2 * m];
      float4 cb = c4[2 * m + 1];
      float dx0 = ca.x - g_cx, dy0 = ca.y - g_cy;
      float d20 = __fmul_rn(dx0, dx0) + __fmul_rn(dy0, dy0);
      float dx1 = ca.z - g_cx, dy1 = ca.w - g_cy;
      float d21 = __fmul_rn(dx1, dx1) + __fmul_rn(dy1, dy1);
      float dx2 = cb.x - g_cx, dy2 = cb.y - g_cy;
      float d22 = __fmul_rn(dx2, dx2) + __fmul_rn(dy2, dy2);
      float dx3 = cb.z - g_cx, dy3 = cb.w - g_cy;
      float d23 = __fmul_rn(dx3, dx3) + __fmul_rn(dy3, dy3);
      if (d20 < thr2) {
        int p = atomicAdd(&s_cnt, 1);
        if (p < CAP) { s_d[p] = __fsqrt_rn(d20); s_i[p] = 4 * m; }
      }
      if (d21 < thr2) {
        int p = atomicAdd(&s_cnt, 1);
        if (p < CAP) { s_d[p] = __fsqrt_rn(d21); s_i[p] = 4 * m + 1; }
      }
      if (d22 < thr2) {
        int p = atomicAdd(&s_cnt, 1);
        if (p < CAP) { s_d[p] = __fsqrt_rn(d22); s_i[p] = 4 * m + 2; }
      }
      if (d23 < thr2) {
        int p = atomicAdd(&s_cnt, 1);
        if (p < CAP) { s_d[p] = __fsqrt_rn(d23); s_i[p] = 4 * m + 3; }
      }
    }
    __syncthreads();
    int cnt = s_cnt;
    __syncthreads();
    if (cnt >= TOPK && cnt <= CAP) { M = cnt; break; }
    thr2 = (cnt < TOPK) ? thr2 * 16.0f : thr2 * 0.25f;
  }

  // --- Exact top-27 by rank counting over (d, idx) lexicographic keys. ---
  // Keys are distinct (idx unique) -> ranks unique; rank k = k-th nearest,
  // same order lax.top_k produces (preserves mean/std sum order).
  for (int s = tid; s < M; s += 1024) {
    unsigned long long pk_s =
        ((unsigned long long)__float_as_uint(s_d[s]) << 20) |
        (unsigned long long)(unsigned)s_i[s];
    int rank = 0;
    for (int j = 0; j < M; ++j) {
      unsigned long long pk_j =
          ((unsigned long long)__float_as_uint(s_d[j]) << 20) |
          (unsigned long long)(unsigned)s_i[j];
      rank += (pk_j < pk_s) ? 1 : 0;
    }
    if (rank < TOPK) s_sel[rank] = s_i[s];
  }
  __syncthreads();

  // --- Candidate IoU + center-inside test. ---
  if (tid < TOPK) {
    int a = s_sel[tid];
    float4 ab = abase[a];
    float area_a = __fmul_rn(ab.z - ab.x, ab.w - ab.y);
    float area_b = __fmul_rn(gbox.z - gbox.x, gbox.w - gbox.y);
    float ltx = fmaxf(ab.x, gbox.x), lty = fmaxf(ab.y, gbox.y);
    float rbx = fminf(ab.z, gbox.z), rby = fminf(ab.w, gbox.w);
    float w = fmaxf(rbx - ltx, 0.0f), h = fmaxf(rby - lty, 0.0f);
    float inter = __fmul_rn(w, h);
    float uni = (area_a + area_b) - inter;
    s_iou[tid] = inter / uni;
    float acx = (ab.z + ab.x) * 0.5f, acy = (ab.w + ab.y) * 0.5f;
    float l = acx - gbox.x, t = acy - gbox.y;
    float r = gbox.z - acx, bt = gbox.w - acy;
    float mn = fminf(fminf(l, t), fminf(r, bt));
    s_in[tid] = (mn > 0.01f) ? 1 : 0;
  }
  __syncthreads();

  // --- mean + unbiased std threshold (ddof=1). Same order as reference. ---
  if (tid == 0) {
    float sum = 0.0f;
    for (int k = 0; k < TOPK; ++k) sum += s_iou[k];
    float mean = sum / (float)TOPK;
    float vs = 0.0f;
    for (int k = 0; k < TOPK; ++k) {
      float d = s_iou[k] - mean;
      vs += __fmul_rn(d, d);
    }
    float sd = __fsqrt_rn(vs / (float)(TOPK - 1));
    s_thresh = mean + sd;
  }
  __syncthreads();

  // --- Scatter positives. ---
  if (tid < TOPK) {
    float iou = s_iou[tid];
    if (s_in[tid] && iou >= s_thresh) {
      unsigned long long pk =
          ((unsigned long long)__float_as_uint(iou) << 32) |
          (unsigned long long)(0xFFFFFFFFu - (unsigned)g);
      atomicMax(&best[(size_t)b * N + s_sel[tid]], pk);
    }
  }
}

// ---------------------------------------------------------------------------
// Kernel B: one block per 256 anchors.
// Phase 1: coalesced best[] load; emit val/idx (dword) and matched_gts
//          (float4) coalesced; stash matched token row index in LDS.
// Phase 2: 64 steps x 4 anchors: block cooperatively streams token rows,
//          4 KB contiguous store per step; loads independent -> pipelined.
// Plain (cached) stores: the harness fill hits 6.2 TB/s on this buffer with
// normal stores; round-2's nontemporal stores are the prime suspect for the
// writer running at ~3 TB/s. Token-row branch is wave-uniform (sub == wave).
// ---------------------------------------------------------------------------
__global__ __launch_bounds__(256) void atss_write_kernel(
    const unsigned long long* __restrict__ best, // [B*N]
    const float* __restrict__ gts,               // [B,G,4]
    const float* __restrict__ tokens,            // [B,G,T]
    float* __restrict__ out)
{
  float* __restrict__ out_val = out;
  float* __restrict__ out_idx = out + (size_t)BN;
  float* __restrict__ out_mg  = out + (size_t)2 * BN;
  float* __restrict__ out_tok = out + (size_t)6 * BN;

  __shared__ int s_row[256]; // gt row (b*G+g) if matched, else -1

  const int tid = threadIdx.x;
  const int i0  = blockIdx.x * 256;
  const int i   = i0 + tid;

  // --- Phase 1 ---
  unsigned long long p = best[i];
  const int b_ = i / N;
  int g = 0;
  float val = NEG_INF_VAL;
  if (p != 0ULL) {
    g   = (int)(0xFFFFFFFFu - (unsigned)(p & 0xFFFFFFFFULL));
    val = __uint_as_float((unsigned)(p >> 32));
  }
  const int row = b_ * G + g; // unmatched -> g=0 (matches argmax of all -INF)
  s_row[tid] = (p != 0ULL) ? row : -1;

  out_val[i] = val;
  out_idx[i] = (float)g;
  ((v4f*)out_mg)[i] = ((const v4f*)gts)[row];
  __syncthreads();

  // --- Phase 2: token rows ---
  const int lane = tid & 63;
  const int sub  = tid >> 6; // 0..3: which anchor within the step (= wave id)
  const v4f* tok4 = (const v4f*)tokens;
#pragma unroll 8
  for (int s = 0; s < 64; ++s) {
    int a = (s << 2) + sub;
    int r = s_row[a];
    v4f t;
    if (r >= 0) {
      t = tok4[(size_t)r * 64 + lane];
    } else {
      t = (v4f){0.0f, 0.0f, 0.0f, 0.0f};
      if (lane == 63) t.w = 1.0f; // unmatched one-hot at token T-1
    }
    ((v4f*)(out_tok + (size_t)(i0 + a) * T))[lane] = t;
  }
}

extern "C" void kernel_launch(void* const* d_in, const int* in_sizes, int n_in,
                              void* d_out, int out_size, void* d_ws, size_t ws_size,
                              hipStream_t stream) {
  const float* anchors = (const float*)d_in[0]; // [B,N,4]
  const float* gts     = (const float*)d_in[1]; // [B,G,4]
  const float* tokens  = (const float*)d_in[2]; // [B,G,T]
  float* out = (float*)d_out;

  unsigned long long* best = (unsigned long long*)d_ws;        // B*N u64 = 6.4 MB
  float2* ctr = (float2*)((char*)d_ws + sizeof(unsigned long long) * (size_t)BN);

  atss_centers_kernel<<<BN / 256, 256, 0, stream>>>(anchors, ctr, best);
  atss_assign_kernel<<<B * G, 1024, 0, stream>>>(anchors, ctr, gts, best);
  atss_write_kernel<<<BN / 256, 256, 0, stream>>>(best, gts, tokens, out);
}

// Round 4
// 846.452 us; speedup vs baseline: 1.1354x; 1.0003x over previous
//
#include <hip/hip_runtime.h>
#include <cstdint>

// Problem constants (fixed dataset: setup_inputs in reference)
constexpr int B = 8, N = 100000, G = 64, T = 256, TOPK = 27;
constexpr int BN = B * N;
constexpr int CAP = 2048;           // candidate LDS capacity per gt
constexpr int TOKEN_BLOCKS = 2048;  // W2 grid: 8192 waves, fill-like sweep
#define NEG_INF_VAL (-100000000.0f) // -INF in reference, exactly representable

typedef float v4f __attribute__((ext_vector_type(4)));

// ---------------------------------------------------------------------------
// Kernel 0: precompute anchor centers (float2) once, and zero the best[]
// buffer (folds the former hipMemsetAsync dispatch into this one).
// Same center formula as the assign/iou phases so distances are bit-identical.
// ---------------------------------------------------------------------------
__global__ __launch_bounds__(256) void atss_centers_kernel(
    const float* __restrict__ anchors, float2* __restrict__ ctr,
    unsigned long long* __restrict__ best)
{
#pragma clang fp contract(off)
  int i = blockIdx.x * 256 + threadIdx.x;
  if (i < BN) {
    float4 ab = ((const float4*)anchors)[i];
    ctr[i] = make_float2((ab.z + ab.x) * 0.5f, (ab.w + ab.y) * 0.5f);
    best[i] = 0ULL;
  }
}

// ---------------------------------------------------------------------------
// Kernel A: one block per (b,g). Exact top-27 nearest anchors by center
// distance (tie-break: lower index, matching lax.top_k), candidate IoUs,
// mean + unbiased std threshold, center-inside test, packed atomicMax
// scatter into per-anchor best buffer.
// packed = (f32bits(iou) << 32) | (0xFFFFFFFF - g)
//   -> max = largest iou; tie -> smallest g (matches jnp.argmax first-max).
// packed == 0 means "unmatched" (positives always have iou > 0).
// ---------------------------------------------------------------------------
__global__ __launch_bounds__(1024) void atss_assign_kernel(
    const float* __restrict__ anchors,     // [B,N,4]
    const float2* __restrict__ ctr,        // [B,N]
    const float* __restrict__ gts,         // [B,G,4]
    unsigned long long* __restrict__ best) // [B*N]
{
#pragma clang fp contract(off)
  __shared__ float s_d[CAP];
  __shared__ int   s_i[CAP];
  __shared__ int   s_cnt;
  __shared__ int   s_sel[TOPK];
  __shared__ float s_iou[TOPK];
  __shared__ int   s_in[TOPK];
  __shared__ float s_thresh;

  // XCD-bijective swizzle: blocks with bid%8==k land on XCD k; map them to
  // batch k (G=64 blocks per batch, 512 = 8*64 total, bijective).
  const int bid = blockIdx.x;
  const int bg  = (bid & 7) * (B * G / 8) + (bid >> 3);
  const int b   = bg / G;
  const int g   = bg % G;
  const int tid = threadIdx.x;

  const float4 gbox = ((const float4*)gts)[bg];
  const float g_cx = (gbox.z + gbox.x) * 0.5f;
  const float g_cy = (gbox.w + gbox.y) * 0.5f;

  const float4*  abase = (const float4*)(anchors + (size_t)b * N * 4);
  const float2*  cbase = ctr + (size_t)b * N;
  const float4*  c4    = (const float4*)cbase;   // 2 anchor centers per load

  // --- Candidate collection: all anchors with d^2 < thr^2 (exact count). ---
  // If the radius captures >= 27 anchors, the true top-27 are all in the set.
  float thr2 = 24.0f * 24.0f;
  int M = 0;
  for (int attempt = 0; attempt < 8; ++attempt) {
    if (tid == 0) s_cnt = 0;
    __syncthreads();
    // 4 anchors per iteration: two independent float4 loads in flight.
    for (int m = tid; m < N / 4; m += 1024) {
      float4 ca = c4[2 * m];
      float4 cb = c4[2 * m + 1];
      float dx0 = ca.x - g_cx, dy0 = ca.y - g_cy;
      float d20 = __fmul_rn(dx0, dx0) + __fmul_rn(dy0, dy0);
      float dx1 = ca.z - g_cx, dy1 = ca.w - g_cy;
      float d21 = __fmul_rn(dx1, dx1) + __fmul_rn(dy1, dy1);
      float dx2 = cb.x - g_cx, dy2 = cb.y - g_cy;
      float d22 = __fmul_rn(dx2, dx2) + __fmul_rn(dy2, dy2);
      float dx3 = cb.z - g_cx, dy3 = cb.w - g_cy;
      float d23 = __fmul_rn(dx3, dx3) + __fmul_rn(dy3, dy3);
      if (d20 < thr2) {
        int p = atomicAdd(&s_cnt, 1);
        if (p < CAP) { s_d[p] = __fsqrt_rn(d20); s_i[p] = 4 * m; }
      }
      if (d21 < thr2) {
        int p = atomicAdd(&s_cnt, 1);
        if (p < CAP) { s_d[p] = __fsqrt_rn(d21); s_i[p] = 4 * m + 1; }
      }
      if (d22 < thr2) {
        int p = atomicAdd(&s_cnt, 1);
        if (p < CAP) { s_d[p] = __fsqrt_rn(d22); s_i[p] = 4 * m + 2; }
      }
      if (d23 < thr2) {
        int p = atomicAdd(&s_cnt, 1);
        if (p < CAP) { s_d[p] = __fsqrt_rn(d23); s_i[p] = 4 * m + 3; }
      }
    }
    __syncthreads();
    int cnt = s_cnt;
    __syncthreads();
    if (cnt >= TOPK && cnt <= CAP) { M = cnt; break; }
    thr2 = (cnt < TOPK) ? thr2 * 16.0f : thr2 * 0.25f;
  }

  // --- Exact top-27 by rank counting over (d, idx) lexicographic keys. ---
  // Keys are distinct (idx unique) -> ranks unique; rank k = k-th nearest,
  // same order lax.top_k produces (preserves mean/std sum order).
  for (int s = tid; s < M; s += 1024) {
    unsigned long long pk_s =
        ((unsigned long long)__float_as_uint(s_d[s]) << 20) |
        (unsigned long long)(unsigned)s_i[s];
    int rank = 0;
    for (int j = 0; j < M; ++j) {
      unsigned long long pk_j =
          ((unsigned long long)__float_as_uint(s_d[j]) << 20) |
          (unsigned long long)(unsigned)s_i[j];
      rank += (pk_j < pk_s) ? 1 : 0;
    }
    if (rank < TOPK) s_sel[rank] = s_i[s];
  }
  __syncthreads();

  // --- Candidate IoU + center-inside test. ---
  if (tid < TOPK) {
    int a = s_sel[tid];
    float4 ab = abase[a];
    float area_a = __fmul_rn(ab.z - ab.x, ab.w - ab.y);
    float area_b = __fmul_rn(gbox.z - gbox.x, gbox.w - gbox.y);
    float ltx = fmaxf(ab.x, gbox.x), lty = fmaxf(ab.y, gbox.y);
    float rbx = fminf(ab.z, gbox.z), rby = fminf(ab.w, gbox.w);
    float w = fmaxf(rbx - ltx, 0.0f), h = fmaxf(rby - lty, 0.0f);
    float inter = __fmul_rn(w, h);
    float uni = (area_a + area_b) - inter;
    s_iou[tid] = inter / uni;
    float acx = (ab.z + ab.x) * 0.5f, acy = (ab.w + ab.y) * 0.5f;
    float l = acx - gbox.x, t = acy - gbox.y;
    float r = gbox.z - acx, bt = gbox.w - acy;
    float mn = fminf(fminf(l, t), fminf(r, bt));
    s_in[tid] = (mn > 0.01f) ? 1 : 0;
  }
  __syncthreads();

  // --- mean + unbiased std threshold (ddof=1). Same order as reference. ---
  if (tid == 0) {
    float sum = 0.0f;
    for (int k = 0; k < TOPK; ++k) sum += s_iou[k];
    float mean = sum / (float)TOPK;
    float vs = 0.0f;
    for (int k = 0; k < TOPK; ++k) {
      float d = s_iou[k] - mean;
      vs += __fmul_rn(d, d);
    }
    float sd = __fsqrt_rn(vs / (float)(TOPK - 1));
    s_thresh = mean + sd;
  }
  __syncthreads();

  // --- Scatter positives. ---
  if (tid < TOPK) {
    float iou = s_iou[tid];
    if (s_in[tid] && iou >= s_thresh) {
      unsigned long long pk =
          ((unsigned long long)__float_as_uint(iou) << 32) |
          (unsigned long long)(0xFFFFFFFFu - (unsigned)g);
      atomicMax(&best[(size_t)b * N + s_sel[tid]], pk);
    }
  }
}

// ---------------------------------------------------------------------------
// Kernel W1: val / idx / matched_gts. One thread per anchor, fully coalesced.
// 19.2 MB of stores + 6.4 MB best[] read: ~5 us.
// ---------------------------------------------------------------------------
__global__ __launch_bounds__(256) void atss_scalar_write_kernel(
    const unsigned long long* __restrict__ best, // [B*N]
    const float* __restrict__ gts,               // [B,G,4]
    float* __restrict__ out)
{
  float* __restrict__ out_val = out;
  float* __restrict__ out_idx = out + (size_t)BN;
  float* __restrict__ out_mg  = out + (size_t)2 * BN;

  const int i = blockIdx.x * 256 + threadIdx.x;
  unsigned long long p = best[i];
  const int b_ = i / N;
  int g = 0;
  float val = NEG_INF_VAL;
  if (p != 0ULL) {
    g   = (int)(0xFFFFFFFFu - (unsigned)(p & 0xFFFFFFFFULL));
    val = __uint_as_float((unsigned)(p >> 32));
  }
  const int row = b_ * G + g; // unmatched -> g=0 (matches argmax of all -INF)
  out_val[i] = val;
  out_idx[i] = (float)g;
  ((v4f*)out_mg)[i] = ((const v4f*)gts)[row];
}

// ---------------------------------------------------------------------------
// Kernel W2: token rows, fill-like global sweep.
// One wave per 1 KB token row; rows assigned GRID-STRIDED (row = wave_id +
// 8192*k) so all 8192 waves march together through a ~8 MB contiguous moving
// window over out_tok -- same DRAM access structure as the 6.2 TB/s harness
// fill, instead of ~2048 private 256 KB streams at random phases (row-buffer
// thrash, ~3.2 TB/s). best[row] is a wave-uniform 8 B broadcast read per KB
// written (+0.8%), software-pipelined one row ahead. row/N division only on
// the ~3% matched path.
// ---------------------------------------------------------------------------
__global__ __launch_bounds__(256) void atss_token_kernel(
    const unsigned long long* __restrict__ best, // [B*N]
    const float* __restrict__ tokens,            // [B,G,T]
    float* __restrict__ out)
{
  float* __restrict__ out_tok = out + (size_t)6 * BN;
  const int lane = threadIdx.x & 63;
  const int NW   = TOKEN_BLOCKS * 4;                       // 8192 waves
  int row = (blockIdx.x << 2) | (threadIdx.x >> 6);        // global wave id
  const v4f* tok4 = (const v4f*)tokens;

  unsigned long long p = best[row];
  while (true) {
    const int nrow = row + NW;
    unsigned long long pn = (nrow < BN) ? best[nrow] : 0ULL; // prefetch next
    v4f t;
    if (p != 0ULL) {
      const int b_ = row / N;
      const int g  = (int)(0xFFFFFFFFu - (unsigned)(p & 0xFFFFFFFFULL));
      t = tok4[(size_t)(b_ * G + g) * 64 + lane];
    } else {
      t = (v4f){0.0f, 0.0f, 0.0f, 0.0f};
      if (lane == 63) t.w = 1.0f; // unmatched one-hot at token T-1
    }
    ((v4f*)(out_tok + (size_t)row * T))[lane] = t;
    if (nrow >= BN) break;
    row = nrow;
    p = pn;
  }
}

extern "C" void kernel_launch(void* const* d_in, const int* in_sizes, int n_in,
                              void* d_out, int out_size, void* d_ws, size_t ws_size,
                              hipStream_t stream) {
  const float* anchors = (const float*)d_in[0]; // [B,N,4]
  const float* gts     = (const float*)d_in[1]; // [B,G,4]
  const float* tokens  = (const float*)d_in[2]; // [B,G,T]
  float* out = (float*)d_out;

  unsigned long long* best = (unsigned long long*)d_ws;        // B*N u64 = 6.4 MB
  float2* ctr = (float2*)((char*)d_ws + sizeof(unsigned long long) * (size_t)BN);

  atss_centers_kernel<<<BN / 256, 256, 0, stream>>>(anchors, ctr, best);
  atss_assign_kernel<<<B * G, 1024, 0, stream>>>(anchors, ctr, gts, best);
  atss_scalar_write_kernel<<<BN / 256, 256, 0, stream>>>(best, gts, out);
  atss_token_kernel<<<TOKEN_BLOCKS, 256, 0, stream>>>(best, tokens, out);
}